// Round 4
// baseline (3926.812 us; speedup 1.0000x reference)
//
#include <hip/hip_runtime.h>

#define B_ 128
#define T_ 512
#define D_ 256
#define H_ 512
#define GG_ 32   // gate groups: 16 hidden units each
#define BG_ 8    // batch groups: 16 rows each

typedef __bf16 bf16x8 __attribute__((ext_vector_type(8)));
typedef float  f32x4  __attribute__((ext_vector_type(4)));
typedef unsigned int u32;
typedef unsigned long long u64;

// h exchange: double-buffered. Element = (bf16 hi)|(bf16 lo<<16) | (tag << 32),
// tag = step+1 (1-based; 0 = cleared). Data IS the flag: consumers poll the
// tagged words directly with relaxed agent-scope atomics — no fences, no
// producer-side drain, no separate flag round trip.
__device__ __align__(16) u64 g_h[2][B_ * H_];

__global__ void clear_tags() {
    int i = blockIdx.x * blockDim.x + threadIdx.x;
    if (i < 2 * B_ * H_) (&g_h[0][0])[i] = 0ull;
}

__device__ inline float sigmoidf_(float v) { return 1.f / (1.f + __expf(-v)); }
__device__ inline float tanhf_(float v)    { return 1.f - 2.f / (__expf(2.f * v) + 1.f); }

// Grid: 256 blocks = 32 gate-groups x 8 batch-groups. Block: 256 threads = 4 waves.
// Wave w owns K-slice [w*64,w*64+64) of D and [w*128,w*128+128) of H.
// Each block computes gates for 16 batch rows x 64 gate rows (4 types x 16 units).
// Weights stay in registers (bf16 hi/lo B-fragments) for all 512 steps.
__global__ __launch_bounds__(256, 1)
void lstm_persistent(const float* __restrict__ x,
                     const float* __restrict__ Wih,
                     const float* __restrict__ Whh,
                     const float* __restrict__ bih,
                     const float* __restrict__ bhh,
                     float* __restrict__ out)
{
    const int tid  = threadIdx.x;
    const int wv   = tid >> 6;
    const int lane = tid & 63;
    const int gg   = blockIdx.x & (GG_ - 1);
    const int bg   = blockIdx.x / GG_;

    const int lm = lane & 15;   // M/N index in 16x16 MFMA tile
    const int lq = lane >> 4;   // k-quad (k offset = lq*8)

    // ---- Weight B-fragments in registers (bf16 hi/lo), loaded once ----
    bf16x8 wih_hi[2][4], wih_lo[2][4];   // [kt][gt], k = wv*64 + kt*32 + lq*8
    bf16x8 whh_hi[4][4], whh_lo[4][4];   // [kt][gt], k = wv*128 + kt*32 + lq*8

    for (int gt = 0; gt < 4; ++gt) {
        const int grow = gt * 512 + gg * 16 + lm;   // gate row (type=gt, unit=gg*16+lm)
#pragma unroll
        for (int kt = 0; kt < 2; ++kt) {
            const float* p = Wih + (size_t)grow * D_ + wv * 64 + kt * 32 + lq * 8;
            bf16x8 hi, lo;
#pragma unroll
            for (int e = 0; e < 8; ++e) {
                float v = p[e];
                __bf16 h1 = (__bf16)v;
                hi[e] = h1; lo[e] = (__bf16)(v - (float)h1);
            }
            wih_hi[kt][gt] = hi; wih_lo[kt][gt] = lo;
        }
#pragma unroll
        for (int kt = 0; kt < 4; ++kt) {
            const float* p = Whh + (size_t)grow * H_ + wv * 128 + kt * 32 + lq * 8;
            bf16x8 hi, lo;
#pragma unroll
            for (int e = 0; e < 8; ++e) {
                float v = p[e];
                __bf16 h1 = (__bf16)v;
                hi[e] = h1; lo[e] = (__bf16)(v - (float)h1);
            }
            whh_hi[kt][gt] = hi; whh_lo[kt][gt] = lo;
        }
    }

    // ---- Pointwise mapping: unit pj = tid&15, batch row pb = tid>>4 ----
    const int pj = tid & 15;
    const int pb = tid >> 4;
    float bias[4];
#pragma unroll
    for (int tp = 0; tp < 4; ++tp) {
        const int r = tp * 512 + gg * 16 + pj;
        bias[tp] = bih[r] + bhh[r];
    }
    float c = 0.f;

    // double-buffered partials => only ONE __syncthreads per step
    __shared__ __align__(16) float gp[2][4][64][17];   // [buf][wave][gate row][batch(+pad)]

    const int   xrow   = bg * 16 + lm;
    const float* xbase = x + (size_t)xrow * T_ * D_ + wv * 64;
    const u32 hoff_r = (u32)(bg * 16 + lm) * H_ + wv * 128;   // consumer fragment base
    const u32 hoff_w = (u32)(bg * 16 + pb) * H_ + gg * 16 + pj;

    for (int t = 0; t < T_; ++t) {
        f32x4 acc[4];
#pragma unroll
        for (int gt = 0; gt < 4; ++gt) acc[gt] = (f32x4){0.f, 0.f, 0.f, 0.f};

        // ---- x-part (independent of h; overlaps the wait for producers) ----
        const float* px = xbase + (size_t)t * D_;
#pragma unroll
        for (int kt = 0; kt < 2; ++kt) {
            const float* p = px + kt * 32 + lq * 8;
            f32x4 v0 = *(const f32x4*)p;
            f32x4 v1 = *(const f32x4*)(p + 4);
            bf16x8 ahi, alo;
#pragma unroll
            for (int e = 0; e < 4; ++e) {
                __bf16 h1 = (__bf16)v0[e];
                ahi[e] = h1; alo[e] = (__bf16)(v0[e] - (float)h1);
                __bf16 h2 = (__bf16)v1[e];
                ahi[e + 4] = h2; alo[e + 4] = (__bf16)(v1[e] - (float)h2);
            }
#pragma unroll
            for (int gt = 0; gt < 4; ++gt) {
                acc[gt] = __builtin_amdgcn_mfma_f32_16x16x32_bf16(ahi, wih_hi[kt][gt], acc[gt], 0, 0, 0);
                acc[gt] = __builtin_amdgcn_mfma_f32_16x16x32_bf16(ahi, wih_lo[kt][gt], acc[gt], 0, 0, 0);
                acc[gt] = __builtin_amdgcn_mfma_f32_16x16x32_bf16(alo, wih_hi[kt][gt], acc[gt], 0, 0, 0);
            }
        }

        // ---- h-part: poll the tagged data itself, then MFMA ----
        if (t > 0) {
            const u64* hp = &g_h[(t - 1) & 1][hoff_r];
            const u32 want = (u32)t;   // producer at step t-1 tagged with (t-1)+1 = t
            u64 v[4][8];
            int ok;
            do {
#pragma unroll
                for (int kt = 0; kt < 4; ++kt)
#pragma unroll
                    for (int e = 0; e < 8; ++e)
                        v[kt][e] = __hip_atomic_load(hp + kt * 32 + lq * 8 + e,
                                                     __ATOMIC_RELAXED, __HIP_MEMORY_SCOPE_AGENT);
                bool mine = true;
#pragma unroll
                for (int kt = 0; kt < 4; ++kt)
#pragma unroll
                    for (int e = 0; e < 8; ++e)
                        mine &= ((u32)(v[kt][e] >> 32) == want);
                ok = __all((int)mine);
                if (!ok) __builtin_amdgcn_s_sleep(1);
            } while (!ok);

#pragma unroll
            for (int kt = 0; kt < 4; ++kt) {
                bf16x8 ahi, alo;
#pragma unroll
                for (int e = 0; e < 8; ++e) {
                    const u32 w = (u32)v[kt][e];
                    ahi[e] = __builtin_bit_cast(__bf16, (unsigned short)(w & 0xffffu));
                    alo[e] = __builtin_bit_cast(__bf16, (unsigned short)(w >> 16));
                }
#pragma unroll
                for (int gt = 0; gt < 4; ++gt) {
                    acc[gt] = __builtin_amdgcn_mfma_f32_16x16x32_bf16(ahi, whh_hi[kt][gt], acc[gt], 0, 0, 0);
                    acc[gt] = __builtin_amdgcn_mfma_f32_16x16x32_bf16(ahi, whh_lo[kt][gt], acc[gt], 0, 0, 0);
                    acc[gt] = __builtin_amdgcn_mfma_f32_16x16x32_bf16(alo, whh_hi[kt][gt], acc[gt], 0, 0, 0);
                }
            }
        }

        // ---- cross-wave K reduction via (double-buffered) LDS ----
        const int buf = t & 1;
#pragma unroll
        for (int gt = 0; gt < 4; ++gt)
            *(f32x4*)&gp[buf][wv][gt * 16 + lm][lq * 4] = acc[gt];   // C/D: col=lm, row=lq*4+reg
        __syncthreads();

        float gate[4];
#pragma unroll
        for (int tp = 0; tp < 4; ++tp) {
            const int g = tp * 16 + pj;
            gate[tp] = gp[buf][0][g][pb] + gp[buf][1][g][pb] +
                       gp[buf][2][g][pb] + gp[buf][3][g][pb] + bias[tp];
        }
        const float ig = sigmoidf_(gate[0]);
        const float fg = sigmoidf_(gate[1]);
        const float gv = tanhf_(gate[2]);
        const float og = sigmoidf_(gate[3]);
        c = fg * c + ig * gv;
        const float h = og * tanhf_(c);

        // ---- publish h immediately (fire-and-forget; data carries its tag) ----
        const __bf16 hh = (__bf16)h;
        const __bf16 hl = (__bf16)(h - (float)hh);
        const u32 packed = (u32)__builtin_bit_cast(unsigned short, hh) |
                           ((u32)__builtin_bit_cast(unsigned short, hl) << 16);
        const u64 word = (u64)packed | ((u64)(u32)(t + 1) << 32);
        __hip_atomic_store(&g_h[t & 1][hoff_w], word, __ATOMIC_RELAXED, __HIP_MEMORY_SCOPE_AGENT);

        out[((size_t)t * B_ + bg * 16 + pb) * H_ + gg * 16 + pj] = h;
    }
}

extern "C" void kernel_launch(void* const* d_in, const int* in_sizes, int n_in,
                              void* d_out, int out_size, void* d_ws, size_t ws_size,
                              hipStream_t stream) {
    const float* x   = (const float*)d_in[0];
    const float* Wih = (const float*)d_in[1];
    const float* Whh = (const float*)d_in[2];
    const float* bih = (const float*)d_in[3];
    const float* bhh = (const float*)d_in[4];
    float* out = (float*)d_out;

    // reset exchange tags every launch (graph replays reuse g_h)
    hipLaunchKernelGGL(clear_tags, dim3((2 * B_ * H_ + 255) / 256), dim3(256), 0, stream);
    hipLaunchKernelGGL(lstm_persistent, dim3(GG_ * BG_), dim3(256), 0, stream,
                       x, Wih, Whh, bih, bhh, out);
}

// Round 6
// 2255.178 us; speedup vs baseline: 1.7412x; 1.7412x over previous
//
#include <hip/hip_runtime.h>

#define B_ 128
#define T_ 512
#define D_ 256
#define H_ 512
#define GG_ 32   // gate groups: 16 hidden units each (32 blocks = one XCD's 32 CUs)
#define BG_ 8    // batch groups: 16 rows each (bg <-> XCD under round-robin dispatch)

typedef __bf16 bf16x8 __attribute__((ext_vector_type(8)));
typedef float  f32x4  __attribute__((ext_vector_type(4)));
typedef unsigned int u32;
typedef unsigned long long u64;
typedef u32    u32x4  __attribute__((ext_vector_type(4)));

// h exchange: T-INDEXED (no reuse => no L1/L2 staleness by construction).
// Element = (bf16 hi) | (bf16 lo << 16). 512 steps x 64K units x 4B = 128 MB.
__device__ __align__(16) u32 g_ht[(size_t)T_ * B_ * H_];
// ready flags, T-indexed: g_rf[t*256 + bg*32 + gg] = 1 when h(t) tile published.
__device__ u32 g_rf[T_ * BG_ * GG_];

__global__ void clear_flags() {
    int i = blockIdx.x * 256 + threadIdx.x;
    if (i < T_ * BG_ * GG_) g_rf[i] = 0u;
}

__device__ inline float sigmoidf_(float v) { return 1.f / (1.f + __expf(-v)); }
__device__ inline float tanhf_(float v)    { return 1.f - 2.f / (__expf(2.f * v) + 1.f); }

// Grid: 256 blocks = 8 bg x 32 gg, bg = blockIdx&7 so one bg's 32 blocks land on
// one XCD under round-robin dispatch (verified at runtime; else agent fallback).
// Block: 256 threads = 4 waves; wave w owns K-slice [w*64,+64) of D, [w*128,+128) of H
// => each wave depends on exactly 8 producer blocks (gg in [8w,8w+8), same bg).
__global__ __launch_bounds__(256, 1)
void lstm_persistent(const float* __restrict__ x,
                     const float* __restrict__ Wih,
                     const float* __restrict__ Whh,
                     const float* __restrict__ bih,
                     const float* __restrict__ bhh,
                     float* __restrict__ out,
                     u32* __restrict__ ws)
{
    const int tid  = threadIdx.x;
    const int wv   = tid >> 6;
    const int lane = tid & 63;
    const int bg   = blockIdx.x & (BG_ - 1);   // XCD-aligned grouping
    const int gg   = blockIdx.x >> 3;

    const int lm = lane & 15;   // M/N index in 16x16 MFMA tile
    const int lq = lane >> 4;   // k-quad (k offset = lq*8)

    // ---- startup: verify all 32 blocks of this bg share one XCD ----
    __shared__ int s_mode;
    if (tid == 0) {
        const u32 xcc = __builtin_amdgcn_s_getreg((31 << 11) | 20);  // HW_REG_XCC_ID
        u32* L = ws + bg;        // leader's xcc+1
        u32* M = ws + 8 + bg;    // vote: low16 = match, high16 = mismatch
        if (gg == 0)
            __hip_atomic_store(L, xcc + 1u, __ATOMIC_RELAXED, __HIP_MEMORY_SCOPE_AGENT);
        u32 lv;
        while ((lv = __hip_atomic_load(L, __ATOMIC_RELAXED, __HIP_MEMORY_SCOPE_AGENT)) == 0u)
            __builtin_amdgcn_s_sleep(2);
        __hip_atomic_fetch_add(M, (lv == xcc + 1u) ? 1u : 0x10000u,
                               __ATOMIC_RELAXED, __HIP_MEMORY_SCOPE_AGENT);
        u32 mv;
        while ((((mv = __hip_atomic_load(M, __ATOMIC_RELAXED, __HIP_MEMORY_SCOPE_AGENT))
                 & 0xffffu) + (mv >> 16)) < (u32)GG_)
            __builtin_amdgcn_s_sleep(2);
        s_mode = (mv == (u32)GG_);
    }
    __syncthreads();
    const bool local_mode = (s_mode != 0);

    // ---- Weight B-fragments in registers (bf16 hi/lo), loaded once ----
    bf16x8 wih_hi[2][4], wih_lo[2][4];   // [kt][gt], k = wv*64 + kt*32 + lq*8
    bf16x8 whh_hi[4][4], whh_lo[4][4];   // [kt][gt], k = wv*128 + kt*32 + lq*8

    for (int gt = 0; gt < 4; ++gt) {
        const int grow = gt * 512 + gg * 16 + lm;   // gate row (type=gt, unit=gg*16+lm)
#pragma unroll
        for (int kt = 0; kt < 2; ++kt) {
            const float* p = Wih + (size_t)grow * D_ + wv * 64 + kt * 32 + lq * 8;
            bf16x8 hi, lo;
#pragma unroll
            for (int e = 0; e < 8; ++e) {
                float v = p[e];
                __bf16 h1 = (__bf16)v;
                hi[e] = h1; lo[e] = (__bf16)(v - (float)h1);
            }
            wih_hi[kt][gt] = hi; wih_lo[kt][gt] = lo;
        }
#pragma unroll
        for (int kt = 0; kt < 4; ++kt) {
            const float* p = Whh + (size_t)grow * H_ + wv * 128 + kt * 32 + lq * 8;
            bf16x8 hi, lo;
#pragma unroll
            for (int e = 0; e < 8; ++e) {
                float v = p[e];
                __bf16 h1 = (__bf16)v;
                hi[e] = h1; lo[e] = (__bf16)(v - (float)h1);
            }
            whh_hi[kt][gt] = hi; whh_lo[kt][gt] = lo;
        }
    }

    // ---- Pointwise mapping: unit pj = tid&15, batch row pb = tid>>4 ----
    const int pj = tid & 15;
    const int pb = tid >> 4;
    float bias[4];
#pragma unroll
    for (int tp = 0; tp < 4; ++tp) {
        const int r = tp * 512 + gg * 16 + pj;
        bias[tp] = bih[r] + bhh[r];
    }
    float c = 0.f;

    __shared__ __align__(16) float gp[4][64][17];   // [wave][gate row][batch(+pad)]

    const int   xrow   = bg * 16 + lm;
    const float* xbase = x + (size_t)xrow * T_ * D_ + wv * 64;
    const u32 hoff_r = (u32)(bg * 16 + lm) * H_ + wv * 128;   // consumer fragment base
    const u32 hoff_w = (u32)(bg * 16 + pb) * H_ + gg * 16 + pj;

    for (int t = 0; t < T_; ++t) {
        f32x4 acc[4];
#pragma unroll
        for (int gt = 0; gt < 4; ++gt) acc[gt] = (f32x4){0.f, 0.f, 0.f, 0.f};

        // ---- x-part (independent of h; overlaps producer wait) ----
        const float* px = xbase + (size_t)t * D_;
#pragma unroll
        for (int kt = 0; kt < 2; ++kt) {
            const float* p = px + kt * 32 + lq * 8;
            f32x4 v0 = *(const f32x4*)p;
            f32x4 v1 = *(const f32x4*)(p + 4);
            bf16x8 ahi, alo;
#pragma unroll
            for (int e = 0; e < 4; ++e) {
                __bf16 h1 = (__bf16)v0[e];
                ahi[e] = h1; alo[e] = (__bf16)(v0[e] - (float)h1);
                __bf16 h2 = (__bf16)v1[e];
                ahi[e + 4] = h2; alo[e + 4] = (__bf16)(v1[e] - (float)h2);
            }
#pragma unroll
            for (int gt = 0; gt < 4; ++gt) {
                acc[gt] = __builtin_amdgcn_mfma_f32_16x16x32_bf16(ahi, wih_hi[kt][gt], acc[gt], 0, 0, 0);
                acc[gt] = __builtin_amdgcn_mfma_f32_16x16x32_bf16(ahi, wih_lo[kt][gt], acc[gt], 0, 0, 0);
                acc[gt] = __builtin_amdgcn_mfma_f32_16x16x32_bf16(alo, wih_hi[kt][gt], acc[gt], 0, 0, 0);
            }
        }

        // ---- h-part: per-wave poll of this wave's 8 producers, then loads ----
        if (t > 0) {
            u32* fb = &g_rf[(u32)(t - 1) * (BG_ * GG_) + bg * GG_ + 8 * wv];
            if (lane < 8) {
                if (local_mode) {
                    // atomic RMW executes at the (shared, XCD-local) L2 — always fresh
                    while (__hip_atomic_fetch_add(fb + lane, 0u, __ATOMIC_RELAXED,
                                                  __HIP_MEMORY_SCOPE_WORKGROUP) == 0u)
                        __builtin_amdgcn_s_sleep(1);
                } else {
                    while (__hip_atomic_load(fb + lane, __ATOMIC_RELAXED,
                                             __HIP_MEMORY_SCOPE_AGENT) == 0u)
                        __builtin_amdgcn_s_sleep(1);
                }
            }
            __builtin_amdgcn_sched_barrier(0);   // keep h loads after the poll

            const u32* hp = &g_ht[(size_t)(t - 1) * (B_ * H_) + hoff_r];
            u32 wd[4][8];
            if (local_mode) {
#pragma unroll
                for (int kt = 0; kt < 4; ++kt) {
                    u32x4 a = *(const u32x4*)(hp + kt * 32 + lq * 8);
                    u32x4 b = *(const u32x4*)(hp + kt * 32 + lq * 8 + 4);
#pragma unroll
                    for (int e = 0; e < 4; ++e) { wd[kt][e] = a[e]; wd[kt][e + 4] = b[e]; }
                }
            } else {
#pragma unroll
                for (int kt = 0; kt < 4; ++kt) {
                    const u64* q = (const u64*)(hp + kt * 32 + lq * 8);
#pragma unroll
                    for (int e = 0; e < 4; ++e) {
                        u64 v = __hip_atomic_load(q + e, __ATOMIC_RELAXED,
                                                  __HIP_MEMORY_SCOPE_AGENT);
                        wd[kt][2 * e] = (u32)v; wd[kt][2 * e + 1] = (u32)(v >> 32);
                    }
                }
            }

#pragma unroll
            for (int kt = 0; kt < 4; ++kt) {
                bf16x8 ahi, alo;
#pragma unroll
                for (int e = 0; e < 8; ++e) {
                    const u32 w = wd[kt][e];
                    ahi[e] = __builtin_bit_cast(__bf16, (unsigned short)(w & 0xffffu));
                    alo[e] = __builtin_bit_cast(__bf16, (unsigned short)(w >> 16));
                }
#pragma unroll
                for (int gt = 0; gt < 4; ++gt) {
                    acc[gt] = __builtin_amdgcn_mfma_f32_16x16x32_bf16(ahi, whh_hi[kt][gt], acc[gt], 0, 0, 0);
                    acc[gt] = __builtin_amdgcn_mfma_f32_16x16x32_bf16(ahi, whh_lo[kt][gt], acc[gt], 0, 0, 0);
                    acc[gt] = __builtin_amdgcn_mfma_f32_16x16x32_bf16(alo, whh_hi[kt][gt], acc[gt], 0, 0, 0);
                }
            }
        }

        // ---- cross-wave K reduction via LDS ----
#pragma unroll
        for (int gt = 0; gt < 4; ++gt)
            *(f32x4*)&gp[wv][gt * 16 + lm][lq * 4] = acc[gt];   // C/D: col=lm, row=lq*4+reg
        __syncthreads();

        float gate[4];
#pragma unroll
        for (int tp = 0; tp < 4; ++tp) {
            const int g = tp * 16 + pj;
            gate[tp] = gp[0][g][pb] + gp[1][g][pb] + gp[2][g][pb] + gp[3][g][pb] + bias[tp];
        }
        const float ig = sigmoidf_(gate[0]);
        const float fg = sigmoidf_(gate[1]);
        const float gv = tanhf_(gate[2]);
        const float og = sigmoidf_(gate[3]);
        c = fg * c + ig * gv;
        const float h = og * tanhf_(c);

        // ---- publish h, drain, signal; out store last (off critical path) ----
        const __bf16 hh = (__bf16)h;
        const __bf16 hl = (__bf16)(h - (float)hh);
        const u32 packed = (u32)__builtin_bit_cast(unsigned short, hh) |
                           ((u32)__builtin_bit_cast(unsigned short, hl) << 16);
        u32* hw = &g_ht[(size_t)t * (B_ * H_) + hoff_w];
        if (local_mode) *hw = packed;   // plain store: write-through to XCD-local L2
        else __hip_atomic_store(hw, packed, __ATOMIC_RELAXED, __HIP_MEMORY_SCOPE_AGENT);

        if (t < T_ - 1) {
            __builtin_amdgcn_sched_barrier(0);   // store must precede the drain
            __builtin_amdgcn_s_waitcnt(0);       // h stores at L2 / coherence point
            __syncthreads();                     // whole tile published
            if (tid == 0) {
                u32* f = &g_rf[(u32)t * (BG_ * GG_) + bg * GG_ + gg];
                if (local_mode) *f = 1u;
                else __hip_atomic_store(f, 1u, __ATOMIC_RELAXED, __HIP_MEMORY_SCOPE_AGENT);
            }
            __builtin_amdgcn_sched_barrier(0);
        }

        out[((size_t)t * B_ + bg * 16 + pb) * H_ + gg * 16 + pj] = h;
    }
}

extern "C" void kernel_launch(void* const* d_in, const int* in_sizes, int n_in,
                              void* d_out, int out_size, void* d_ws, size_t ws_size,
                              hipStream_t stream) {
    const float* x   = (const float*)d_in[0];
    const float* Wih = (const float*)d_in[1];
    const float* Whh = (const float*)d_in[2];
    const float* bih = (const float*)d_in[3];
    const float* bhh = (const float*)d_in[4];
    float* out = (float*)d_out;
    u32* ws = (u32*)d_ws;

    hipMemsetAsync(d_ws, 0, 4096, stream);   // startup-vote words (ws poisoned 0xAA)
    hipLaunchKernelGGL(clear_flags, dim3((T_ * BG_ * GG_ + 255) / 256), dim3(256), 0, stream);
    hipLaunchKernelGGL(lstm_persistent, dim3(GG_ * BG_), dim3(256), 0, stream,
                       x, Wih, Whh, bih, bhh, out, ws);
}